// Round 4
// baseline (508.730 us; speedup 1.0000x reference)
//
#include <hip/hip_runtime.h>

// Problem constants (fixed by reference: B=4,S=4096,IN=1024,OUT=4096,RANK=32)
#define B_DIM 4
#define S_DIM 4096
#define IN_DIM 1024
#define OUT_DIM 4096
#define RANK_DIM 32

#define M_DIM (B_DIM * S_DIM)   // 16384
#define N_DIM OUT_DIM           // 4096
#define K_DIM IN_DIM            // 1024

#define CVT_BLOCKS ((M_DIM * K_DIM) / 1024)  // 16384 blocks for x-cast

typedef _Float16 h4 __attribute__((ext_vector_type(4)));
typedef _Float16 h8 __attribute__((ext_vector_type(8)));
typedef float f32x4 __attribute__((ext_vector_type(4)));

// Async global->LDS, 16B per lane. LDS dest = wave-uniform base + lane*16.
__device__ __forceinline__ void async_load16(const void* g, void* l) {
  __builtin_amdgcn_global_load_lds((const __attribute__((address_space(1))) void*)g,
                                   (__attribute__((address_space(3))) void*)l,
                                   16, 0, 0);
}

// ---------------------------------------------------------------------------
// Fused prep (unchanged; ~25-30 us):
// blocks [0, CVT_BLOCKS) cast x fp32->f16; blocks [CVT_BLOCKS, +OUT_DIM)
// build one row of w_eff = weight + w1[src] @ w2[tgt], cast to f16.
// ---------------------------------------------------------------------------
__global__ __launch_bounds__(256) void prep_fused_kernel(
    const float4* __restrict__ x, h4* __restrict__ xh,
    const float* __restrict__ weight, const float* __restrict__ w1,
    const float* __restrict__ w2, const int* __restrict__ src_id,
    const int* __restrict__ tgt_id, h4* __restrict__ weff) {
  if (blockIdx.x < CVT_BLOCKS) {
    const int i = blockIdx.x * 256 + threadIdx.x;
    const float4 v = x[i];
    h4 o;
    o[0] = (_Float16)v.x; o[1] = (_Float16)v.y;
    o[2] = (_Float16)v.z; o[3] = (_Float16)v.w;
    xh[i] = o;
  } else {
    const int n = blockIdx.x - CVT_BLOCKS;    // 0..4095
    const int src = src_id[0];
    const int tgt = tgt_id[0];
    __shared__ float w1r[RANK_DIM];
    if (threadIdx.x < RANK_DIM)
      w1r[threadIdx.x] = w1[((size_t)src * OUT_DIM + n) * RANK_DIM + threadIdx.x];
    __syncthreads();
    const int k4 = threadIdx.x;               // 0..255 (= IN/4)
    float4 acc = ((const float4*)(weight + (size_t)n * IN_DIM))[k4];
    const float* w2t = w2 + (size_t)tgt * RANK_DIM * IN_DIM;
#pragma unroll 8
    for (int r = 0; r < RANK_DIM; ++r) {
      const float4 wv = ((const float4*)(w2t + (size_t)r * IN_DIM))[k4];
      const float c = w1r[r];
      acc.x += c * wv.x; acc.y += c * wv.y; acc.z += c * wv.z; acc.w += c * wv.w;
    }
    h4 o;
    o[0] = (_Float16)acc.x; o[1] = (_Float16)acc.y;
    o[2] = (_Float16)acc.z; o[3] = (_Float16)acc.w;
    weff[(size_t)n * (IN_DIM / 4) + k4] = o;
  }
}

// ---------------------------------------------------------------------------
// m201-template GEMM: 256x256 tile, 8 waves (2M x 4N, 128x64 per wave),
// BK=64 via mfma_f32_16x16x32_f16, LDS [2 buf][2 khalf][256 rows x 32 halfs]
// (64-byte rows: a k-half is CONTIGUOUS -> global_load_lds stage-able as
// 2 loads/thread; 64B rows also spread frag reads over 8 bank-groups,
// killing the 4-way conflict that cost round-0 ~16%).
// Per tile, 4 phases (khalf kh x Mhalf mh): {4 A ds_read_b128 (+4 B when
// mh==0; B-frags cached across mh) | stage ONE half-tile of tile t+1 |
// s_barrier | setprio(1) 16 MFMA setprio(0) | [vmcnt(4)] s_barrier}.
// vmcnt(4) twice per tile (end of P1 and P3): retires exactly the half-tiles
// the NEXT phase reads, keeps 4 loads in flight across every barrier (m218:
// counted, never drain-0 in steady state). FIFO retirement audit:
//   end-P3(t): outstanding {A-K0,B-K0,A-K1,B-K1}(t+1)=8 -> keep newest 4
//              -> K0(t+1) landed, needed by P0(t+1).  OK
//   end-P1(t): outstanding {A-K1,B-K1}(t) + {A-K0,B-K0}(t+1)=8 -> keep 4
//              -> K1(t) landed, needed by P2(t).      OK
// Last tile peeled: no staging, vmcnt(0) at end-P1 (nothing left to cover).
// ---------------------------------------------------------------------------
__global__ __launch_bounds__(512, 2) void lms_gemm256_kernel(
    const _Float16* __restrict__ A,   // [M][K] f16
    const _Float16* __restrict__ Bt,  // [N][K] f16
    const float* __restrict__ bias,   // [N]
    float* __restrict__ C) {          // [M][N]
  __shared__ _Float16 sA[2][2][8192];  // [buf][khalf][256*32] = 64 KiB
  __shared__ _Float16 sB[2][2][8192];  // 64 KiB

  const int tid = threadIdx.x;
  const int wave = tid >> 6;
  const int lane = tid & 63;

  // XCD-aware bijective swizzle (1024 wg % 8 == 0).
  const int bid = blockIdx.x;                 // 0..1023
  const int wg = (bid & 7) * 128 + (bid >> 3);
  const int bm = wg >> 4;                     // 0..63
  const int bn = wg & 15;                     // 0..15

  const int wr = wave >> 2;                   // 0..1  (M half of tile)
  const int wc = wave & 3;                    // 0..3  (N quarter)
  const int fl = lane & 15;                   // frag row/col
  const int ch = lane >> 4;                   // frag k-chunk (8 halfs)

  // Staging map: thread tid covers row = 128*i + (tid>>2), chunk = tid&3 of a
  // [256][32]-half half-tile; LDS dest (wave-uniform) = half_base + wave*512
  // (+4096 for i=1); HW appends lane*16B. Dest/src row-chunk audit:
  // dest unit w*64+lane -> row w*16+(lane>>2), chunk lane&3 == src. OK
  const _Float16* gA = A + (size_t)(bm * 256 + (tid >> 2)) * K_DIM + (tid & 3) * 8;
  const _Float16* gB = Bt + (size_t)(bn * 256 + (tid >> 2)) * K_DIM + (tid & 3) * 8;

  f32x4 acc[8][4] = {};
  h8 bf[4];

#define STG_A(NB, KH, KN)                                                     \
  {                                                                           \
    async_load16(gA + (KN) + (KH) * 32, &sA[NB][KH][wave * 512]);             \
    async_load16(gA + (KN) + (KH) * 32 + (size_t)128 * K_DIM,                 \
                 &sA[NB][KH][4096 + wave * 512]);                             \
  }
#define STG_B(NB, KH, KN)                                                     \
  {                                                                           \
    async_load16(gB + (KN) + (KH) * 32, &sB[NB][KH][wave * 512]);             \
    async_load16(gB + (KN) + (KH) * 32 + (size_t)128 * K_DIM,                 \
                 &sB[NB][KH][4096 + wave * 512]);                             \
  }
#define VM4 asm volatile("s_waitcnt vmcnt(4)" ::: "memory")
#define VM0 asm volatile("s_waitcnt vmcnt(0)" ::: "memory")
#define VM_NONE
#define NOSTG

// Phase: A-frags (4 x b128), B-frags when mh==0 (4 x b128, cached to mh==1),
// one half-tile stage, barrier, MFMA cluster, optional vmcnt, barrier.
// Compiler inserts the lgkmcnt waits for the frag->MFMA data deps (G7).
#define PHASE(CB, KH, MH, STAGE_STMT, TRAIL)                                  \
  {                                                                           \
    h8 af[4];                                                                 \
    _Pragma("unroll") for (int mi = 0; mi < 4; ++mi)                          \
      af[mi] = *(const h8*)&sA[CB][KH]                                        \
          [(wr * 128 + (MH) * 64 + mi * 16 + fl) * 32 + ch * 8];              \
    if ((MH) == 0) {                                                          \
      _Pragma("unroll") for (int ni = 0; ni < 4; ++ni)                        \
        bf[ni] = *(const h8*)&sB[CB][KH]                                      \
            [(wc * 64 + ni * 16 + fl) * 32 + ch * 8];                         \
    }                                                                         \
    STAGE_STMT;                                                               \
    __builtin_amdgcn_s_barrier();                                             \
    __builtin_amdgcn_s_setprio(1);                                            \
    _Pragma("unroll") for (int mi = 0; mi < 4; ++mi)                          \
      _Pragma("unroll") for (int ni = 0; ni < 4; ++ni)                        \
        acc[(MH) * 4 + mi][ni] = __builtin_amdgcn_mfma_f32_16x16x32_f16(      \
            af[mi], bf[ni], acc[(MH) * 4 + mi][ni], 0, 0, 0);                 \
    __builtin_amdgcn_s_setprio(0);                                            \
    TRAIL;                                                                    \
    __builtin_amdgcn_s_barrier();                                             \
  }

  // Prologue: stage tile0's 4 half-tiles; retire K0 halves only; rendezvous.
  STG_A(0, 0, 0);
  STG_B(0, 0, 0);
  STG_A(0, 1, 0);
  STG_B(0, 1, 0);
  asm volatile("s_waitcnt vmcnt(4)" ::: "memory");
  __builtin_amdgcn_s_barrier();

  // Tiles 0..13, two per iteration (compile-time buffer roles).
#pragma unroll 1
  for (int it = 0; it < 7; ++it) {
    const int kn0 = it * 128 + 64;   // K-offset of tile 2it+1 (staged now)
    const int kn1 = kn0 + 64;        // K-offset of tile 2it+2
    PHASE(0, 0, 0, STG_A(1, 0, kn0), VM_NONE);
    PHASE(0, 0, 1, STG_B(1, 0, kn0), VM4);
    PHASE(0, 1, 0, STG_A(1, 1, kn0), VM_NONE);
    PHASE(0, 1, 1, STG_B(1, 1, kn0), VM4);
    PHASE(1, 0, 0, STG_A(0, 0, kn1), VM_NONE);
    PHASE(1, 0, 1, STG_B(0, 0, kn1), VM4);
    PHASE(1, 1, 0, STG_A(0, 1, kn1), VM_NONE);
    PHASE(1, 1, 1, STG_B(0, 1, kn1), VM4);
  }
  // Tile 14 (buf 0): stages tile 15 (K-offset 960).
  PHASE(0, 0, 0, STG_A(1, 0, 960), VM_NONE);
  PHASE(0, 0, 1, STG_B(1, 0, 960), VM4);
  PHASE(0, 1, 0, STG_A(1, 1, 960), VM_NONE);
  PHASE(0, 1, 1, STG_B(1, 1, 960), VM4);
  // Tile 15 (buf 1): no staging; drain K1 halves before P2 (end of pipeline).
  PHASE(1, 0, 0, NOSTG, VM_NONE);
  PHASE(1, 0, 1, NOSTG, VM0);
  PHASE(1, 1, 0, NOSTG, VM_NONE);
  PHASE(1, 1, 1, NOSTG, VM_NONE);

  // Epilogue: 16x16 C/D layout col = lane&15, row = (lane>>4)*4 + reg
  // [m89/m91 verified].
#pragma unroll
  for (int ni = 0; ni < 4; ++ni) {
    const int col = bn * 256 + wc * 64 + ni * 16 + fl;
    const float bv = bias[col];
#pragma unroll
    for (int mi = 0; mi < 8; ++mi) {
      const int rowb = bm * 256 + wr * 128 + mi * 16 + ch * 4;
      float* cp = C + (size_t)rowb * N_DIM + col;
#pragma unroll
      for (int r = 0; r < 4; ++r) {
        cp[(size_t)r * N_DIM] = acc[mi][ni][r] + bv;
      }
    }
  }
}

extern "C" void kernel_launch(void* const* d_in, const int* in_sizes, int n_in,
                              void* d_out, int out_size, void* d_ws, size_t ws_size,
                              hipStream_t stream) {
  const float* x      = (const float*)d_in[0];  // [4,4096,1024]
  const float* weight = (const float*)d_in[1];  // [4096,1024]
  const float* bias   = (const float*)d_in[2];  // [4096]
  const float* w1     = (const float*)d_in[3];  // [9,4096,32]
  const float* w2     = (const float*)d_in[4];  // [9,32,1024]
  const int* src_id   = (const int*)d_in[5];    // scalar
  const int* tgt_id   = (const int*)d_in[6];    // scalar
  float* out          = (float*)d_out;          // [4,4096,4096]

  // Workspace layout: x_f16 (32 MiB) | w_eff_f16 (8 MiB). Rewritten fully
  // every call (harness re-poisons d_ws).
  _Float16* xh   = (_Float16*)d_ws;
  _Float16* weff = xh + (size_t)M_DIM * K_DIM;

  prep_fused_kernel<<<CVT_BLOCKS + N_DIM, 256, 0, stream>>>(
      (const float4*)x, (h4*)xh, weight, w1, w2, src_id, tgt_id, (h4*)weff);

  lms_gemm256_kernel<<<dim3(1024), dim3(512), 0, stream>>>(xh, weff, bias, out);
}